// Round 1
// baseline (200.642 us; speedup 1.0000x reference)
//
#include <hip/hip_runtime.h>

// Problem: B=8, S=512, NQ=12, L=4, 2^NQ = 4096 amplitudes.
// out = [psi_Q | psi_K | psi_V], each (B*S, 4096) fp32, concat flat.
//
// Single fused kernel, 4 samples/block, 3 barriers:
//  A1: 144 threads build per-layer Rz·Ry·Rz matrices (3 sincosf each);
//      48 threads sincos the angles.
//  A2: 36 threads fold 4 layers (3 complex 2x2 matmuls) -> U, then apply to
//      [cos,sin] for all 4 samples -> vv.
//  C : 4-qubit group products -> AB (qubits 0-3, 4-7), Plo (qubits 8-11).
//  E : BATCHED — per sample, all 27 LDS float2 reads are pulled into
//      registers first, then 12 float4 stores issue as a pure burst with no
//      ds ops between them. Rationale: the previous per-j interleave put an
//      lgkmcnt wait between store clusters; if stores share the lgkm counter
//      (flat lowering) or the scheduler honors each wait, store issue gets
//      paced at LDS latency instead of streaming. Fill kernel proves writes
//      saturate (6.8 TB/s) at 10% occupancy, so streaming is all we need.
// Round-3 lesson: nontemporal stores cost ~5-10 us vs plain stores here.

#define BS_TOTAL 4096   // B*S = 8*512
#define NQ 12
#define NL 4
#define NSTATE 4096     // 2^12
#define SPB 4           // samples per block

__device__ __forceinline__ float2 cmul(float2 a, float2 b) {
    return make_float2(a.x * b.x - a.y * b.y, a.x * b.y + a.y * b.x);
}
__device__ __forceinline__ float2 cconj(float2 a) { return make_float2(a.x, -a.y); }
__device__ __forceinline__ float2 cadd(float2 a, float2 b) { return make_float2(a.x + b.x, a.y + b.y); }

__global__ __launch_bounds__(256, 4) void vqc_fused_kernel(
    const float* __restrict__ angles,       // (B*S, 12)
    const float* __restrict__ tQ,           // (L, NQ, 3)
    const float* __restrict__ tK,
    const float* __restrict__ tV,
    float* __restrict__ out)                // (3, B*S, 4096)
{
    const int bs0 = blockIdx.x * SPB;
    const int t   = threadIdx.x;            // 0 .. 255

    __shared__ float2 Lm[36][NL][4];        // per-layer 2x2 matrices   (4608 B)
    __shared__ float  cs[SPB][NQ][2];       // cos/sin(angle/2)          (384 B)
    __shared__ float2 vv[SPB][3][NQ][2];    // per-qubit 2-vectors      (2304 B)
    __shared__ float2 AB[SPB][3][2][16];    // qubits 0-3 / 4-7         (3072 B)
    __shared__ float2 Plo[SPB][3][16];      // qubits 8-11              (1536 B)

    // ---- Phase A1: 144 threads build one layer matrix each; 48 load angles ----
    if (t < 144) {
        int l = t & 3, mn = t >> 2, m = mn / NQ, n = mn % NQ;
        const float* th = (m == 0) ? tQ : (m == 1) ? tK : tV;   // (L, NQ, 3)
        float c = 0.5f * th[(l * NQ + n) * 3 + 0];  // inner Rz
        float b = 0.5f * th[(l * NQ + n) * 3 + 1];  // Ry
        float a = 0.5f * th[(l * NQ + n) * 3 + 2];  // outer Rz
        float sa, ca, sb, cb, sc, cc;
        sincosf(a, &sa, &ca);
        sincosf(b, &sb, &cb);
        sincosf(c, &sc, &cc);
        float2 ea = {ca, -sa};                 // exp(-i a)
        float2 ec = {cc, -sc};                 // exp(-i c)
        float2 p  = cmul(ea, ec);
        float2 q  = cmul(ea, cconj(ec));
        Lm[mn][l][0] = make_float2( cb * p.x,  cb * p.y);
        Lm[mn][l][1] = make_float2(-sb * q.x, -sb * q.y);
        Lm[mn][l][2] = make_float2( sb * q.x, -sb * q.y);   // sb * conj(q)
        Lm[mn][l][3] = make_float2( cb * p.x, -cb * p.y);   // cb * conj(p)
    } else if (t >= 160 && t < 160 + SPB * NQ) {
        int idx = t - 160, s2 = idx / NQ, n = idx % NQ;
        float a = angles[(bs0 + s2) * NQ + n];
        float s, c;
        sincosf(0.5f * a, &s, &c);
        cs[s2][n][0] = c; cs[s2][n][1] = s;
    }
    __syncthreads();

    // ---- Phase A2: 36 threads fold 4 layers -> U, then vv for all samples ----
    if (t < 36) {
        int m = t / NQ, n = t % NQ;
        float2 U00 = Lm[t][0][0], U01 = Lm[t][0][1], U10 = Lm[t][0][2], U11 = Lm[t][0][3];
#pragma unroll
        for (int l = 1; l < NL; ++l) {
            float2 A00 = Lm[t][l][0], A01 = Lm[t][l][1], A10 = Lm[t][l][2], A11 = Lm[t][l][3];
            float2 n00 = cadd(cmul(A00, U00), cmul(A01, U10));
            float2 n01 = cadd(cmul(A00, U01), cmul(A01, U11));
            float2 n10 = cadd(cmul(A10, U00), cmul(A11, U10));
            float2 n11 = cadd(cmul(A10, U01), cmul(A11, U11));
            U00 = n00; U01 = n01; U10 = n10; U11 = n11;
        }
#pragma unroll
        for (int s2 = 0; s2 < SPB; ++s2) {
            float c = cs[s2][n][0], s = cs[s2][n][1];
            vv[s2][m][n][0] = make_float2(U00.x * c + U01.x * s, U00.y * c + U01.y * s);
            vv[s2][m][n][1] = make_float2(U10.x * c + U11.x * s, U10.y * c + U11.y * s);
        }
    }
    __syncthreads();

    // ---- Phase C: 4-qubit group products (SPB*144 = 576 tasks) ----
#pragma unroll
    for (int task = t; task < SPB * 144; task += 256) {
        int s2 = task / 144, r = task % 144, m = r / 48, g = (r % 48) / 16, idx = r % 16;
        int q0 = g * 4;
        float2 p = cmul(cmul(vv[s2][m][q0    ][(idx >> 3) & 1],
                             vv[s2][m][q0 + 1][(idx >> 2) & 1]),
                        cmul(vv[s2][m][q0 + 2][(idx >> 1) & 1],
                             vv[s2][m][q0 + 3][ idx       & 1]));
        if (g < 2) AB[s2][m][g][idx] = p; else Plo[s2][m][idx] = p;
    }
    __syncthreads();

    // ---- Phase E: k = j*1024 + t*4 + i; hi = j*4+(t>>6) (x) (t>>2)&15;
    //      lo = 4*(t&3)+i. Per sample: batch ALL 27 LDS reads into registers,
    //      then a pure burst of 12 coalesced float4 stores (no ds ops between
    //      stores -> no lgkm waits can pace the store stream). ----
    const int lobase = 4 * (t & 3);
    const int hi_lo  = (t >> 2) & 15;
    const int hi_hi  = t >> 6;              // wave-uniform
#pragma unroll
    for (int s2 = 0; s2 < SPB; ++s2) {
        float2 L0[3], L1[3], L2[3], L3[3], B1[3], A0[3][4];
#pragma unroll
        for (int m = 0; m < 3; ++m) {
            L0[m] = Plo[s2][m][lobase + 0];
            L1[m] = Plo[s2][m][lobase + 1];
            L2[m] = Plo[s2][m][lobase + 2];
            L3[m] = Plo[s2][m][lobase + 3];
            B1[m] = AB[s2][m][1][hi_lo];
#pragma unroll
            for (int j = 0; j < 4; ++j) {
                A0[m][j] = AB[s2][m][0][j * 4 + hi_hi];
            }
        }
#pragma unroll
        for (int m = 0; m < 3; ++m) {
            float* po = out + (size_t)m * ((size_t)BS_TOTAL * NSTATE)
                            + (size_t)(bs0 + s2) * NSTATE + t * 4;
#pragma unroll
            for (int j = 0; j < 4; ++j) {
                float2 h = cmul(A0[m][j], B1[m]);
                float4 r;
                r.x = h.x * L0[m].x - h.y * L0[m].y;   // Re(h * l)
                r.y = h.x * L1[m].x - h.y * L1[m].y;
                r.z = h.x * L2[m].x - h.y * L2[m].y;
                r.w = h.x * L3[m].x - h.y * L3[m].y;
                *(float4*)(po + j * 1024) = r;
            }
        }
    }
}

extern "C" void kernel_launch(void* const* d_in, const int* in_sizes, int n_in,
                              void* d_out, int out_size, void* d_ws, size_t ws_size,
                              hipStream_t stream) {
    (void)in_sizes; (void)n_in; (void)out_size; (void)d_ws; (void)ws_size;
    const float* angles = (const float*)d_in[0];   // (8,512,12)
    const float* tQ     = (const float*)d_in[1];   // (4,12,3)
    const float* tK     = (const float*)d_in[2];
    const float* tV     = (const float*)d_in[3];

    vqc_fused_kernel<<<BS_TOTAL / SPB, 256, 0, stream>>>(angles, tQ, tK, tV, (float*)d_out);
}

// Round 2
// 200.632 us; speedup vs baseline: 1.0001x; 1.0001x over previous
//
#include <hip/hip_runtime.h>

// Problem: B=8, S=512, NQ=12, L=4, 2^NQ = 4096 amplitudes.
// out = [psi_Q | psi_K | psi_V], each (B*S, 4096) fp32, concat flat.
//
// Single fused kernel, 8 samples/block (512 blocks, 2 blocks/CU), 3 barriers:
//  A1: 144 threads build per-layer Rz·Ry·Rz matrices (3 sincosf each);
//      96 threads sincos the angles (8 samples x 12 qubits).
//  A2: 36 threads fold 4 layers (3 complex 2x2 matmuls) -> U, then apply to
//      [cos,sin] for all 8 samples -> vv.
//  C : 4-qubit group products -> AB (qubits 0-3, 4-7), Plo (qubits 8-11).
//  E : m-OUTER, s2-INNER: per matrix m the block sweeps a CONTIGUOUS 128-KiB
//      output run (8 consecutive samples), 9 LDS float2 reads then 4 float4
//      stores per (m,s2). Rationale: fill kernel writes one contiguous
//      sliding window at 6.8 TB/s; previous 1024-block/12-stream layout had
//      12,288 scattered 16-KiB write streams. This cuts streams 8x and
//      halves prologue cost per output byte.
// Round-3 lesson (prev session): nontemporal stores cost ~5-10 us here.
// R1 lesson: phase-E LDS/store interleave is NOT the limiter (batched reads
//      + pure store burst was neutral vs interleaved).

#define BS_TOTAL 4096   // B*S = 8*512
#define NQ 12
#define NL 4
#define NSTATE 4096     // 2^12
#define SPB 8           // samples per block

__device__ __forceinline__ float2 cmul(float2 a, float2 b) {
    return make_float2(a.x * b.x - a.y * b.y, a.x * b.y + a.y * b.x);
}
__device__ __forceinline__ float2 cconj(float2 a) { return make_float2(a.x, -a.y); }
__device__ __forceinline__ float2 cadd(float2 a, float2 b) { return make_float2(a.x + b.x, a.y + b.y); }

__global__ __launch_bounds__(256, 4) void vqc_fused_kernel(
    const float* __restrict__ angles,       // (B*S, 12)
    const float* __restrict__ tQ,           // (L, NQ, 3)
    const float* __restrict__ tK,
    const float* __restrict__ tV,
    float* __restrict__ out)                // (3, B*S, 4096)
{
    const int bs0 = blockIdx.x * SPB;
    const int t   = threadIdx.x;            // 0 .. 255

    __shared__ float2 Lm[36][NL][4];        // per-layer 2x2 matrices   (4608 B)
    __shared__ float  cs[SPB][NQ][2];       // cos/sin(angle/2)          (768 B)
    __shared__ float2 vv[SPB][3][NQ][2];    // per-qubit 2-vectors      (4608 B)
    __shared__ float2 AB[SPB][3][2][16];    // qubits 0-3 / 4-7         (6144 B)
    __shared__ float2 Plo[SPB][3][16];      // qubits 8-11              (3072 B)

    // ---- Phase A1: 144 threads build one layer matrix each; 96 load angles ----
    if (t < 144) {
        int l = t & 3, mn = t >> 2, m = mn / NQ, n = mn % NQ;
        const float* th = (m == 0) ? tQ : (m == 1) ? tK : tV;   // (L, NQ, 3)
        float c = 0.5f * th[(l * NQ + n) * 3 + 0];  // inner Rz
        float b = 0.5f * th[(l * NQ + n) * 3 + 1];  // Ry
        float a = 0.5f * th[(l * NQ + n) * 3 + 2];  // outer Rz
        float sa, ca, sb, cb, sc, cc;
        sincosf(a, &sa, &ca);
        sincosf(b, &sb, &cb);
        sincosf(c, &sc, &cc);
        float2 ea = {ca, -sa};                 // exp(-i a)
        float2 ec = {cc, -sc};                 // exp(-i c)
        float2 p  = cmul(ea, ec);
        float2 q  = cmul(ea, cconj(ec));
        Lm[mn][l][0] = make_float2( cb * p.x,  cb * p.y);
        Lm[mn][l][1] = make_float2(-sb * q.x, -sb * q.y);
        Lm[mn][l][2] = make_float2( sb * q.x, -sb * q.y);   // sb * conj(q)
        Lm[mn][l][3] = make_float2( cb * p.x, -cb * p.y);   // cb * conj(p)
    } else if (t >= 160 && t < 160 + SPB * NQ) {
        int idx = t - 160, s2 = idx / NQ, n = idx % NQ;
        float a = angles[(bs0 + s2) * NQ + n];
        float s, c;
        sincosf(0.5f * a, &s, &c);
        cs[s2][n][0] = c; cs[s2][n][1] = s;
    }
    __syncthreads();

    // ---- Phase A2: 36 threads fold 4 layers -> U, then vv for all samples ----
    if (t < 36) {
        int m = t / NQ, n = t % NQ;
        float2 U00 = Lm[t][0][0], U01 = Lm[t][0][1], U10 = Lm[t][0][2], U11 = Lm[t][0][3];
#pragma unroll
        for (int l = 1; l < NL; ++l) {
            float2 A00 = Lm[t][l][0], A01 = Lm[t][l][1], A10 = Lm[t][l][2], A11 = Lm[t][l][3];
            float2 n00 = cadd(cmul(A00, U00), cmul(A01, U10));
            float2 n01 = cadd(cmul(A00, U01), cmul(A01, U11));
            float2 n10 = cadd(cmul(A10, U00), cmul(A11, U10));
            float2 n11 = cadd(cmul(A10, U01), cmul(A11, U11));
            U00 = n00; U01 = n01; U10 = n10; U11 = n11;
        }
#pragma unroll
        for (int s2 = 0; s2 < SPB; ++s2) {
            float c = cs[s2][n][0], s = cs[s2][n][1];
            vv[s2][m][n][0] = make_float2(U00.x * c + U01.x * s, U00.y * c + U01.y * s);
            vv[s2][m][n][1] = make_float2(U10.x * c + U11.x * s, U10.y * c + U11.y * s);
        }
    }
    __syncthreads();

    // ---- Phase C: 4-qubit group products (SPB*144 = 1152 tasks) ----
    for (int task = t; task < SPB * 144; task += 256) {
        int s2 = task / 144, r = task % 144, m = r / 48, g = (r % 48) / 16, idx = r % 16;
        int q0 = g * 4;
        float2 p = cmul(cmul(vv[s2][m][q0    ][(idx >> 3) & 1],
                             vv[s2][m][q0 + 1][(idx >> 2) & 1]),
                        cmul(vv[s2][m][q0 + 2][(idx >> 1) & 1],
                             vv[s2][m][q0 + 3][ idx       & 1]));
        if (g < 2) AB[s2][m][g][idx] = p; else Plo[s2][m][idx] = p;
    }
    __syncthreads();

    // ---- Phase E: k = j*1024 + t*4 + i; hi = j*4+(t>>6) (x) (t>>2)&15;
    //      lo = 4*(t&3)+i. m OUTER, s2 INNER: each m is one contiguous
    //      128-KiB sweep (8 consecutive samples). Per (m,s2): 9 broadcast /
    //      conflict-free LDS float2 reads, then 4 coalesced float4 stores
    //      (1 KiB per wave-instruction). ----
    const int lobase = 4 * (t & 3);
    const int hi_lo  = (t >> 2) & 15;
    const int hi_hi  = t >> 6;              // wave-uniform
#pragma unroll
    for (int m = 0; m < 3; ++m) {
        float* pm = out + (size_t)m * ((size_t)BS_TOTAL * NSTATE)
                        + (size_t)bs0 * NSTATE + t * 4;
#pragma unroll
        for (int s2 = 0; s2 < SPB; ++s2) {
            float2 l0 = Plo[s2][m][lobase + 0];
            float2 l1 = Plo[s2][m][lobase + 1];
            float2 l2 = Plo[s2][m][lobase + 2];
            float2 l3 = Plo[s2][m][lobase + 3];
            float2 b1 = AB[s2][m][1][hi_lo];
            float* po = pm + (size_t)s2 * NSTATE;
#pragma unroll
            for (int j = 0; j < 4; ++j) {
                float2 h = cmul(AB[s2][m][0][j * 4 + hi_hi], b1);
                float4 r;
                r.x = h.x * l0.x - h.y * l0.y;   // Re(h * l)
                r.y = h.x * l1.x - h.y * l1.y;
                r.z = h.x * l2.x - h.y * l2.y;
                r.w = h.x * l3.x - h.y * l3.y;
                *(float4*)(po + j * 1024) = r;
            }
        }
    }
}

extern "C" void kernel_launch(void* const* d_in, const int* in_sizes, int n_in,
                              void* d_out, int out_size, void* d_ws, size_t ws_size,
                              hipStream_t stream) {
    (void)in_sizes; (void)n_in; (void)out_size; (void)d_ws; (void)ws_size;
    const float* angles = (const float*)d_in[0];   // (8,512,12)
    const float* tQ     = (const float*)d_in[1];   // (4,12,3)
    const float* tK     = (const float*)d_in[2];
    const float* tV     = (const float*)d_in[3];

    vqc_fused_kernel<<<BS_TOTAL / SPB, 256, 0, stream>>>(angles, tQ, tK, tV, (float*)d_out);
}